// Round 1
// 376.845 us; speedup vs baseline: 1.2476x; 1.2476x over previous
//
#include <hip/hip_runtime.h>
#include <math.h>

#define BB 8
#define CC 512
#define LL 4096
#define DQK 64

typedef short short8 __attribute__((ext_vector_type(8)));
typedef unsigned short ushort4v __attribute__((ext_vector_type(4)));
typedef unsigned short ushort8v __attribute__((ext_vector_type(8)));
typedef float floatx4 __attribute__((ext_vector_type(4)));
typedef unsigned int uint4v __attribute__((ext_vector_type(4)));

__device__ __forceinline__ unsigned short f2bf(float f) {
    union { float f; unsigned u; } v; v.f = f;
    unsigned r = v.u + 0x7fffu + ((v.u >> 16) & 1u);
    return (unsigned short)(r >> 16);
}

// async global->LDS DMA, 16B per lane. LDS dest is wave-uniform base + lane*16.
__device__ __forceinline__ void load_lds16(const void* gptr, void* lptr) {
    __builtin_amdgcn_global_load_lds(
        (const __attribute__((address_space(1))) unsigned int*)gptr,
        (__attribute__((address_space(3))) unsigned int*)lptr, 16, 0, 0);
}

__device__ __forceinline__ unsigned cvt_pk_bf16(float lo, float hi) {
    unsigned r;
    asm("v_cvt_pk_bf16_f32 %0, %1, %2" : "=v"(r) : "v"(lo), "v"(hi));
    return r;
}

// ---------------- transpose + cast: xt[b][l][c] = bf16(x[b][c][l]) ----------------
__global__ __launch_bounds__(256) void k_transpose(const float* __restrict__ x,
                                                   unsigned short* __restrict__ xt) {
    __shared__ unsigned short tile[64][72];
    int l0 = blockIdx.x * 64, c0 = blockIdx.y * 64, b = blockIdx.z;
    int t = threadIdx.x;
    int r  = t >> 2;              // c-row 0..63
    int ch = (t & 3) * 16;        // l-chunk
    const float* src = x + ((size_t)b * CC + c0 + r) * LL + l0 + ch;
#pragma unroll
    for (int j = 0; j < 4; ++j) {
        floatx4 v = *(const floatx4*)(src + j * 4);
        ushort4v u = { f2bf(v[0]), f2bf(v[1]), f2bf(v[2]), f2bf(v[3]) };
        *(ushort4v*)(&tile[r][ch + j * 4]) = u;
    }
    __syncthreads();
    int lr  = t >> 2;             // l-row 0..63
    int cch = (t & 3) * 16;       // c-chunk
    ushort8v o0, o1;
#pragma unroll
    for (int j = 0; j < 8; ++j) o0[j] = tile[cch + j][lr];
#pragma unroll
    for (int j = 0; j < 8; ++j) o1[j] = tile[cch + 8 + j][lr];
    unsigned short* dst = xt + ((size_t)b * LL + l0 + lr) * CC + c0 + cch;
    *(ushort8v*)(dst)     = o0;
    *(ushort8v*)(dst + 8) = o1;
}

// ---------------- weight cast ----------------
__global__ void k_castw(const float* __restrict__ wq, const float* __restrict__ wk,
                        const float* __restrict__ wv,
                        unsigned short* __restrict__ wqb, unsigned short* __restrict__ wkb,
                        unsigned short* __restrict__ wvb) {
    int i = blockIdx.x * 256 + threadIdx.x;   // grid covers 262144
    if (i < DQK * CC) { wqb[i] = f2bf(wq[i]); wkb[i] = f2bf(wk[i]); }
    wvb[i] = f2bf(wv[i]);
}

// ---------------- q/k projection: out[b][l][d]; W (64x512) staged in LDS ----------------
// scale: LOG2E folded into q so attention uses raw v_exp_f32 (exp2).
__global__ __launch_bounds__(256) void k_proj(const unsigned short* __restrict__ xt,
                                              const unsigned short* __restrict__ wb,
                                              const float* __restrict__ bias,
                                              unsigned short* __restrict__ out,
                                              float scale) {
    int l0 = blockIdx.x * 64;
    int b  = blockIdx.y;
    int tid = threadIdx.x;
    int w = tid >> 6, lane = tid & 63;
    int lane16 = lane & 15, g = lane >> 4;
    __shared__ unsigned short wtile[64 * 512];
    {
        int pg = tid & 63;
#pragma unroll
        for (int ci = 0; ci < 16; ++ci) {
            int r  = ci * 4 + (tid >> 6);
            int sg = (pg & 56) | ((pg ^ r) & 7);
            load_lds16(wb + (size_t)r * CC + sg * 8, wtile + ((size_t)ci * 256 + tid) * 8);
        }
    }
    const unsigned short* xrow = xt + ((size_t)b * LL + l0 + w * 16 + lane16) * CC + g * 8;
    short8 afrag[16];
#pragma unroll
    for (int kk = 0; kk < 16; ++kk) afrag[kk] = *(const short8*)(xrow + kk * 32);
    __syncthreads();

    int xe = (g ^ (lane16 & 7)) * 8;          // kk even granule offset
    int xo = ((g + 4) ^ (lane16 & 7)) * 8;    // kk odd
#pragma unroll
    for (int nt = 0; nt < 4; ++nt) {
        int dl = nt * 16 + lane16;
        floatx4 acc = {0.f, 0.f, 0.f, 0.f};
#pragma unroll
        for (int kk = 0; kk < 16; ++kk) {
            int off = dl * 512 + (kk >> 1) * 64 + ((kk & 1) ? xo : xe);
            short8 bfrag = *(const short8*)(wtile + off);
            acc = __builtin_amdgcn_mfma_f32_16x16x32_bf16(afrag[kk], bfrag, acc, 0, 0, 0);
        }
        float bv = bias[dl];
#pragma unroll
        for (int r = 0; r < 4; ++r) {
            int lidx = l0 + w * 16 + g * 4 + r;
            out[((size_t)b * LL + lidx) * DQK + dl] = f2bf((acc[r] + bv) * scale);
        }
    }
}

// ---------------- v projection: out[b][d][l], all 512 d per block (z looped) ----------------
__global__ __launch_bounds__(256) void k_projT(const unsigned short* __restrict__ xt,
                                               const unsigned short* __restrict__ wb,
                                               const float* __restrict__ bias,
                                               unsigned short* __restrict__ out) {
    int l0 = blockIdx.x * 64;
    int b  = blockIdx.y;
    int tid = threadIdx.x;
    int w = tid >> 6, lane = tid & 63;
    int lane16 = lane & 15, g = lane >> 4;
    __shared__ unsigned short xtile[64 * 512];
    {
        const unsigned short* xg = xt + ((size_t)b * LL + l0) * CC;
        int pg = tid & 63;
#pragma unroll
        for (int ci = 0; ci < 16; ++ci) {
            int r  = ci * 4 + (tid >> 6);
            int sg = (pg & 56) | ((pg ^ r) & 7);
            load_lds16(xg + (size_t)r * CC + sg * 8, xtile + ((size_t)ci * 256 + tid) * 8);
        }
    }
    __syncthreads();

    int xe = (g ^ (lane16 & 7)) * 8;
    int xo = ((g + 4) ^ (lane16 & 7)) * 8;
    for (int z = 0; z < 8; ++z) {
        int dw = z * 64 + w * 16;
        const unsigned short* wrow = wb + (size_t)(dw + lane16) * CC + g * 8;
        short8 afrag[16];
#pragma unroll
        for (int kk = 0; kk < 16; ++kk) afrag[kk] = *(const short8*)(wrow + kk * 32);
#pragma unroll
        for (int nt = 0; nt < 4; ++nt) {
            floatx4 acc = {0.f, 0.f, 0.f, 0.f};
#pragma unroll
            for (int kk = 0; kk < 16; ++kk) {
                int off = (nt * 16 + lane16) * 512 + (kk >> 1) * 64 + ((kk & 1) ? xo : xe);
                short8 bfrag = *(const short8*)(xtile + off);
                acc = __builtin_amdgcn_mfma_f32_16x16x32_bf16(afrag[kk], bfrag, acc, 0, 0, 0);
            }
            int l = l0 + nt * 16 + lane16;
#pragma unroll
            for (int r = 0; r < 4; ++r) {
                int d = dw + g * 4 + r;
                out[((size_t)b * CC + d) * LL + l] = f2bf(acc[r] + bias[d]);
            }
        }
    }
}

// ---------------- fused flash attention ----------------
// grid: (L/128, B, C/256). 4 waves x 32 q-rows.
// Changes vs prev round:
//  * swapped QK^T: S^T = mfma(K,Q) -> lane holds P for fixed i=lane16; P->A-frag
//    repack is IN-REGISTER (cvt_pk_bf16 + permlane32/16_swap) -> pbuf LDS deleted
//    (removes 2.1M bank conflicts + ~128 VALU converts per wave-tile).
//  * l (softmax denom) via ones-column MFMA on packed P: C-layout row=g*4+r lands
//    exactly where the epilogue needs it; no shuffles, no per-elem adds.
//  * LOG2E pre-folded into q (k_proj scale) -> raw v_exp_f32.
//  * K/V double-buffered (80 KB, still 2 blocks/CU): one __syncthreads per tile,
//    next tile's global_load_lds issued before compute -> staging latency hidden.
__global__ __launch_bounds__(256, 2) void k_attn(const unsigned short* __restrict__ q,
                                                 const unsigned short* __restrict__ kws,
                                                 const unsigned short* __restrict__ vws,
                                                 const float* __restrict__ x,
                                                 const float* __restrict__ gamma,
                                                 float* __restrict__ out) {
    int i0 = blockIdx.x * 128;
    int b  = blockIdx.y;
    int c0 = blockIdx.z * 256;
    int tid = threadIdx.x;
    int w = tid >> 6, lane = tid & 63;
    int lane16 = lane & 15, g = lane >> 4;
    int iw = i0 + w * 32;

    __shared__ unsigned short kt[2][64 * 64];    // 2 x  8 KB: K tile [j][d], swizzled
    __shared__ unsigned short vt[2][256 * 64];   // 2 x 32 KB: V tile [c][j], swizzled

    // Q fragments (B-operand of swapped QK^T: col=lane16 -> q-row i)
    short8 qf[2][2];
#pragma unroll
    for (int m = 0; m < 2; ++m) {
        const unsigned short* qrow = q + ((size_t)b * LL + iw + m * 16 + lane16) * DQK + g * 8;
        qf[m][0] = *(const short8*)(qrow);
        qf[m][1] = *(const short8*)(qrow + 32);
    }

    const unsigned short* kglob = kws + (size_t)b * LL * DQK;
    const unsigned short* vglob = vws + ((size_t)b * CC + c0) * LL;
    int gr    = (tid & 7) ^ ((tid >> 3) & 7);
    int koff0 = (tid >> 3) * DQK + gr * 8;
    int voff0 = (tid >> 3) * LL  + gr * 8;

    // fragment read offsets (ushort units) within one buffer
    int kro[2], vro[2];
#pragma unroll
    for (int kk = 0; kk < 2; ++kk) {
        int sw = (kk * 4 + g) ^ (lane16 & 7);
        kro[kk] = lane16 * 64 + sw * 8;
        vro[kk] = lane16 * 64 + sw * 8;
    }

    short8 ones;
#pragma unroll
    for (int j = 0; j < 8; ++j) ones[j] = (short)0x3f80;   // bf16 1.0

    floatx4 O[2][16];
#pragma unroll
    for (int m = 0; m < 2; ++m)
#pragma unroll
        for (int nt = 0; nt < 16; ++nt) O[m][nt] = {0.f, 0.f, 0.f, 0.f};
    floatx4 Ol[2];
#pragma unroll
    for (int m = 0; m < 2; ++m) Ol[m] = {0.f, 0.f, 0.f, 0.f};

    auto stage = [&](int j0n, int buf) {
        const unsigned short* ks = kglob + j0n * DQK + koff0;
        unsigned short* kd = &kt[buf][tid * 8];
        load_lds16(ks, kd);
        load_lds16(ks + 2048, kd + 2048);
        const unsigned short* vs = vglob + j0n + voff0;
        unsigned short* vd = &vt[buf][tid * 8];
#pragma unroll
        for (int i = 0; i < 8; ++i)
            load_lds16(vs + i * 131072, vd + i * 2048);
    };

    stage(0, 0);
    int cur = 0;
    for (int j0 = 0; j0 < LL; j0 += 64) {
        __syncthreads();                      // buf[cur] DMA drained; prev reads of buf[cur^1] done
        if (j0 + 64 < LL) stage(j0 + 64, cur ^ 1);

        const unsigned short* kb = kt[cur];
        const unsigned short* vb = vt[cur];

        // ---- S^T = K * Q^T : col = i (lane16), row = j (g*4+r, per nt) ----
        floatx4 S[2][4];
#pragma unroll
        for (int m = 0; m < 2; ++m)
#pragma unroll
            for (int nt = 0; nt < 4; ++nt) S[m][nt] = {0.f, 0.f, 0.f, 0.f};
#pragma unroll
        for (int nt = 0; nt < 4; ++nt) {
            short8 k0 = *(const short8*)(kb + kro[0] + nt * 1024);
#pragma unroll
            for (int m = 0; m < 2; ++m)
                S[m][nt] = __builtin_amdgcn_mfma_f32_16x16x32_bf16(k0, qf[m][0], S[m][nt], 0, 0, 0);
        }
#pragma unroll
        for (int nt = 0; nt < 4; ++nt) {
            short8 k1 = *(const short8*)(kb + kro[1] + nt * 1024);
#pragma unroll
            for (int m = 0; m < 2; ++m)
                S[m][nt] = __builtin_amdgcn_mfma_f32_16x16x32_bf16(k1, qf[m][1], S[m][nt], 0, 0, 0);
        }

        // ---- direct exp2 (LOG2E pre-folded) + in-register repack to A-frags ----
        short8 pa[2][2];
#pragma unroll
        for (int m = 0; m < 2; ++m) {
#pragma unroll
            for (int kk = 0; kk < 2; ++kk) {
                floatx4 p0, p1;
#pragma unroll
                for (int r = 0; r < 4; ++r) {
                    p0[r] = __builtin_amdgcn_exp2f(S[m][2 * kk][r]);
                    p1[r] = __builtin_amdgcn_exp2f(S[m][2 * kk + 1][r]);
                }
                unsigned A0 = cvt_pk_bf16(p0[0], p0[1]);
                unsigned A1 = cvt_pk_bf16(p0[2], p0[3]);
                unsigned B0 = cvt_pk_bf16(p1[0], p1[1]);
                unsigned B1 = cvt_pk_bf16(p1[2], p1[3]);
                // lane algebra: after swap32, A0=[A0r0,A0r1,B0r0,B0r1], B0=[A0r2,A0r3,B0r2,B0r3];
                // after swap16, A0=word0, B0=word2 of the PV A-frag (A1/B1 -> word1/word3).
                asm("v_permlane32_swap_b32 %0, %1" : "+v"(A0), "+v"(B0));
                asm("v_permlane16_swap_b32 %0, %1" : "+v"(A0), "+v"(B0));
                asm("v_permlane32_swap_b32 %0, %1" : "+v"(A1), "+v"(B1));
                asm("v_permlane16_swap_b32 %0, %1" : "+v"(A1), "+v"(B1));
                uint4v pw = { A0, A1, B0, B1 };
                pa[m][kk] = *(short8*)&pw;
            }
            // softmax denominator: ones-column MFMA, C-layout row = g*4+r (matches O)
#pragma unroll
            for (int kk = 0; kk < 2; ++kk)
                Ol[m] = __builtin_amdgcn_mfma_f32_16x16x32_bf16(pa[m][kk], ones, Ol[m], 0, 0, 0);
        }

        // ---- O += P * V ----
        __builtin_amdgcn_s_setprio(1);
#pragma unroll
        for (int kk = 0; kk < 2; ++kk)
#pragma unroll
            for (int nt = 0; nt < 16; ++nt) {
                short8 vf = *(const short8*)(vb + vro[kk] + nt * 1024);
#pragma unroll
                for (int m = 0; m < 2; ++m)
                    O[m][nt] = __builtin_amdgcn_mfma_f32_16x16x32_bf16(pa[m][kk], vf, O[m][nt], 0, 0, 0);
            }
        __builtin_amdgcn_s_setprio(0);
        cur ^= 1;
    }

    // ---- epilogue: out = gamma * O / l + x ----
    float linv[2][4];
#pragma unroll
    for (int m = 0; m < 2; ++m)
#pragma unroll
        for (int r = 0; r < 4; ++r) linv[m][r] = 1.f / Ol[m][r];

    float gam = gamma[0];
#pragma unroll
    for (int m = 0; m < 2; ++m)
#pragma unroll
        for (int nt = 0; nt < 16; ++nt) {
            int c = c0 + nt * 16 + lane16;
            size_t base = ((size_t)b * CC + c) * LL + iw + m * 16 + g * 4;
            floatx4 xv = *(const floatx4*)(x + base);
            floatx4 o;
#pragma unroll
            for (int r = 0; r < 4; ++r) o[r] = gam * (O[m][nt][r] * linv[m][r]) + xv[r];
            *(floatx4*)(out + base) = o;
        }
}

extern "C" void kernel_launch(void* const* d_in, const int* in_sizes, int n_in,
                              void* d_out, int out_size, void* d_ws, size_t ws_size,
                              hipStream_t stream) {
    const float* x     = (const float*)d_in[0];
    const float* Wq    = (const float*)d_in[1];
    const float* bq    = (const float*)d_in[2];
    const float* Wk    = (const float*)d_in[3];
    const float* bk    = (const float*)d_in[4];
    const float* Wv    = (const float*)d_in[5];
    const float* bv    = (const float*)d_in[6];
    const float* gamma = (const float*)d_in[7];
    float* out = (float*)d_out;

    unsigned short* xt  = (unsigned short*)d_ws;          // B*L*C      = 16,777,216
    unsigned short* qb  = xt  + (size_t)BB * LL * CC;     // B*L*64     =  2,097,152
    unsigned short* kb  = qb  + (size_t)BB * LL * DQK;
    unsigned short* vb  = kb  + (size_t)BB * LL * DQK;    // B*C*L      = 16,777,216
    unsigned short* wqb = vb  + (size_t)BB * CC * LL;     // 32768
    unsigned short* wkb = wqb + (size_t)DQK * CC;
    unsigned short* wvb = wkb + (size_t)DQK * CC;         // 262144

    const float LOG2E = 1.4426950408889634f;
    k_transpose<<<dim3(LL / 64, CC / 64, BB), 256, 0, stream>>>(x, xt);
    k_castw<<<dim3((CC * CC) / 256), 256, 0, stream>>>(Wq, Wk, Wv, wqb, wkb, wvb);
    k_proj<<<dim3(LL / 64, BB), 256, 0, stream>>>(xt, wqb, bq, qb, LOG2E);
    k_proj<<<dim3(LL / 64, BB), 256, 0, stream>>>(xt, wkb, bk, kb, 1.0f);
    k_projT<<<dim3(LL / 64, BB), 256, 0, stream>>>(xt, wvb, bv, vb);
    k_attn<<<dim3(LL / 128, BB, CC / 256), 256, 0, stream>>>(qb, kb, vb, x, gamma, out);
}

// Round 2
// 356.521 us; speedup vs baseline: 1.3187x; 1.0570x over previous
//
#include <hip/hip_runtime.h>
#include <math.h>

#define BB 8
#define CC 512
#define LL 4096
#define DQK 64

typedef short short8 __attribute__((ext_vector_type(8)));
typedef unsigned short ushort4v __attribute__((ext_vector_type(4)));
typedef unsigned short ushort8v __attribute__((ext_vector_type(8)));
typedef float floatx4 __attribute__((ext_vector_type(4)));
typedef unsigned int uint4v __attribute__((ext_vector_type(4)));

__device__ __forceinline__ unsigned short f2bf(float f) {
    union { float f; unsigned u; } v; v.f = f;
    unsigned r = v.u + 0x7fffu + ((v.u >> 16) & 1u);
    return (unsigned short)(r >> 16);
}

// async global->LDS DMA, 16B per lane. LDS dest is wave-uniform base + lane*16.
__device__ __forceinline__ void load_lds16(const void* gptr, void* lptr) {
    __builtin_amdgcn_global_load_lds(
        (const __attribute__((address_space(1))) unsigned int*)gptr,
        (__attribute__((address_space(3))) unsigned int*)lptr, 16, 0, 0);
}

__device__ __forceinline__ unsigned cvt_pk_bf16(float lo, float hi) {
    unsigned r;
    asm("v_cvt_pk_bf16_f32 %0, %1, %2" : "=v"(r) : "v"(lo), "v"(hi));
    return r;
}

// ---------------- transpose + cast: xt[b][l][c] = bf16(x[b][c][l]) ----------------
__global__ __launch_bounds__(256) void k_transpose(const float* __restrict__ x,
                                                   unsigned short* __restrict__ xt) {
    __shared__ unsigned short tile[64][72];
    int l0 = blockIdx.x * 64, c0 = blockIdx.y * 64, b = blockIdx.z;
    int t = threadIdx.x;
    int r  = t >> 2;              // c-row 0..63
    int ch = (t & 3) * 16;        // l-chunk
    const float* src = x + ((size_t)b * CC + c0 + r) * LL + l0 + ch;
#pragma unroll
    for (int j = 0; j < 4; ++j) {
        floatx4 v = *(const floatx4*)(src + j * 4);
        ushort4v u = { f2bf(v[0]), f2bf(v[1]), f2bf(v[2]), f2bf(v[3]) };
        *(ushort4v*)(&tile[r][ch + j * 4]) = u;
    }
    __syncthreads();
    int lr  = t >> 2;             // l-row 0..63
    int cch = (t & 3) * 16;       // c-chunk
    ushort8v o0, o1;
#pragma unroll
    for (int j = 0; j < 8; ++j) o0[j] = tile[cch + j][lr];
#pragma unroll
    for (int j = 0; j < 8; ++j) o1[j] = tile[cch + 8 + j][lr];
    unsigned short* dst = xt + ((size_t)b * LL + l0 + lr) * CC + c0 + cch;
    *(ushort8v*)(dst)     = o0;
    *(ushort8v*)(dst + 8) = o1;
}

// ---------------- weight cast ----------------
__global__ void k_castw(const float* __restrict__ wq, const float* __restrict__ wk,
                        const float* __restrict__ wv,
                        unsigned short* __restrict__ wqb, unsigned short* __restrict__ wkb,
                        unsigned short* __restrict__ wvb) {
    int i = blockIdx.x * 256 + threadIdx.x;   // grid covers 262144
    if (i < DQK * CC) { wqb[i] = f2bf(wq[i]); wkb[i] = f2bf(wk[i]); }
    wvb[i] = f2bf(wv[i]);
}

// ---------------- fused q/k/v projection ----------------
// One block per (64-l tile, b). xt tile (64 l x 512 c, 64 KB) staged ONCE in LDS
// via swizzled global_load_lds; W A-frags from global (L2-hot, 640 KB total) with
// double-buffered prefetch: z+1's 16 frags issued before z's 64 MFMAs.
// z<8: V rows (out [d][l]);  z==8: Q (out [l][d], LOG2E folded);  z==9: K (out [l][d]).
__global__ __launch_bounds__(256) void k_projall(const unsigned short* __restrict__ xt,
                                                 const unsigned short* __restrict__ wqb,
                                                 const unsigned short* __restrict__ wkb,
                                                 const unsigned short* __restrict__ wvb,
                                                 const float* __restrict__ bq,
                                                 const float* __restrict__ bk,
                                                 const float* __restrict__ bv,
                                                 unsigned short* __restrict__ qout,
                                                 unsigned short* __restrict__ kout,
                                                 unsigned short* __restrict__ vout) {
    int l0 = blockIdx.x * 64;
    int b  = blockIdx.y;
    int tid = threadIdx.x;
    int w = tid >> 6, lane = tid & 63;
    int lane16 = lane & 15, g = lane >> 4;
    __shared__ unsigned short xtile[64 * 512];
    {
        const unsigned short* xg = xt + ((size_t)b * LL + l0) * CC;
        int pg = tid & 63;
#pragma unroll
        for (int ci = 0; ci < 16; ++ci) {
            int r  = ci * 4 + (tid >> 6);
            int sg = (pg & 56) | ((pg ^ r) & 7);
            load_lds16(xg + (size_t)r * CC + sg * 8, xtile + ((size_t)ci * 256 + tid) * 8);
        }
    }

    int xe = (g ^ (lane16 & 7)) * 8;
    int xo = ((g + 4) ^ (lane16 & 7)) * 8;

    auto loadW = [&](short8 (&af)[16], int z) {
        const unsigned short* base;
        if (z < 8)       base = wvb + (size_t)(z * 64 + w * 16 + lane16) * CC;
        else if (z == 8) base = wqb + (size_t)(w * 16 + lane16) * CC;
        else             base = wkb + (size_t)(w * 16 + lane16) * CC;
        base += g * 8;
#pragma unroll
        for (int kk = 0; kk < 16; ++kk) af[kk] = *(const short8*)(base + kk * 32);
    };

    auto comp = [&](short8 (&af)[16], int z) {
#pragma unroll
        for (int nt = 0; nt < 4; ++nt) {
            floatx4 acc = {0.f, 0.f, 0.f, 0.f};
#pragma unroll
            for (int kk = 0; kk < 16; ++kk) {
                int off = (nt * 16 + lane16) * 512 + (kk >> 1) * 64 + ((kk & 1) ? xo : xe);
                short8 bfrag = *(const short8*)(xtile + off);
                acc = __builtin_amdgcn_mfma_f32_16x16x32_bf16(af[kk], bfrag, acc, 0, 0, 0);
            }
            int l = l0 + nt * 16 + lane16;
            if (z < 8) {
#pragma unroll
                for (int r = 0; r < 4; ++r) {
                    int d = z * 64 + w * 16 + g * 4 + r;
                    vout[((size_t)b * CC + d) * LL + l] = f2bf(acc[r] + bv[d]);
                }
            } else {
                const float* bias = (z == 8) ? bq : bk;
                float sc = (z == 8) ? 1.4426950408889634f : 1.0f;
                ushort4v o;
#pragma unroll
                for (int r = 0; r < 4; ++r)
                    o[r] = f2bf((acc[r] + bias[w * 16 + g * 4 + r]) * sc);
                unsigned short* dst = ((z == 8) ? qout : kout)
                                      + ((size_t)b * LL + l) * DQK + w * 16 + g * 4;
                *(ushort4v*)dst = o;
            }
        }
    };

    short8 afA[16], afB[16];
    loadW(afA, 0);
    __syncthreads();   // xtile DMA drained

    for (int z = 0; z < 10; z += 2) {
        loadW(afB, z + 1);             // prefetch next-z W under this z's MFMAs
        comp(afA, z);
        if (z + 2 < 10) loadW(afA, z + 2);
        comp(afB, z + 1);
    }
}

// ---------------- fused flash attention ----------------
// grid: (L/128, B, C/256). 4 waves x 32 q-rows.
// Round-2 changes:
//  * j-tile split into two independent 32-j halves: S(h1) MFMAs overlap exp/repack(h0),
//    PV(h0) overlaps exp/repack(h1) -> fills the matrix pipe during softmax VALU bursts.
//  * K-frags batched (4 ds_read_b128 up front per half).
//  * XCD-aware block remap: the 32 blocks sharing one (b,z) K/V working set (2.5 MB,
//    L2-fit) get hw bids = same residue mod 8 -> same XCD L2.
__global__ __launch_bounds__(256, 2) void k_attn(const unsigned short* __restrict__ q,
                                                 const unsigned short* __restrict__ kws,
                                                 const unsigned short* __restrict__ vws,
                                                 const float* __restrict__ x,
                                                 const float* __restrict__ gamma,
                                                 float* __restrict__ out) {
    // bijective remap: hw bid -> (bx, by, bz); group g=(b,z) of 32 blocks -> XCD g&7
    int bid = blockIdx.x + 32 * blockIdx.y + 256 * blockIdx.z;
    int x8  = bid & 7;
    int ii  = bid >> 3;                  // 0..63
    int wg  = (x8 + 8 * (ii >> 5)) * 32 + (ii & 31);
    int i0 = (wg & 31) * 128;
    int b  = (wg >> 5) & 7;
    int c0 = (wg >> 8) * 256;

    int tid = threadIdx.x;
    int w = tid >> 6, lane = tid & 63;
    int lane16 = lane & 15, g = lane >> 4;
    int iw = i0 + w * 32;

    __shared__ unsigned short kt[2][64 * 64];    // 2 x  8 KB: K tile [j][d], swizzled
    __shared__ unsigned short vt[2][256 * 64];   // 2 x 32 KB: V tile [c][j], swizzled

    // Q fragments (B-operand of swapped QK^T: col=lane16 -> q-row i)
    short8 qf[2][2];
#pragma unroll
    for (int m = 0; m < 2; ++m) {
        const unsigned short* qrow = q + ((size_t)b * LL + iw + m * 16 + lane16) * DQK + g * 8;
        qf[m][0] = *(const short8*)(qrow);
        qf[m][1] = *(const short8*)(qrow + 32);
    }

    const unsigned short* kglob = kws + (size_t)b * LL * DQK;
    const unsigned short* vglob = vws + ((size_t)b * CC + c0) * LL;
    int gr    = (tid & 7) ^ ((tid >> 3) & 7);
    int koff0 = (tid >> 3) * DQK + gr * 8;
    int voff0 = (tid >> 3) * LL  + gr * 8;

    // fragment read offsets (ushort units) within one buffer
    int kro[2], vro[2];
#pragma unroll
    for (int kk = 0; kk < 2; ++kk) {
        int sw = (kk * 4 + g) ^ (lane16 & 7);
        kro[kk] = lane16 * 64 + sw * 8;
        vro[kk] = lane16 * 64 + sw * 8;
    }

    short8 ones;
#pragma unroll
    for (int j = 0; j < 8; ++j) ones[j] = (short)0x3f80;   // bf16 1.0

    floatx4 O[2][16];
#pragma unroll
    for (int m = 0; m < 2; ++m)
#pragma unroll
        for (int nt = 0; nt < 16; ++nt) O[m][nt] = {0.f, 0.f, 0.f, 0.f};
    floatx4 Ol[2];
#pragma unroll
    for (int m = 0; m < 2; ++m) Ol[m] = {0.f, 0.f, 0.f, 0.f};

    auto stage = [&](int j0n, int buf) {
        const unsigned short* ks = kglob + j0n * DQK + koff0;
        unsigned short* kd = &kt[buf][tid * 8];
        load_lds16(ks, kd);
        load_lds16(ks + 2048, kd + 2048);
        const unsigned short* vs = vglob + j0n + voff0;
        unsigned short* vd = &vt[buf][tid * 8];
#pragma unroll
        for (int i = 0; i < 8; ++i)
            load_lds16(vs + i * 131072, vd + i * 2048);
    };

    // exp + in-register repack + ones-MFMA for one 32-j half
    auto softmax_half = [&](floatx4 (&Sh)[2][2], short8 (&paD)[2]) {
#pragma unroll
        for (int m = 0; m < 2; ++m) {
            float e0[4], e1[4];
#pragma unroll
            for (int r = 0; r < 4; ++r) {
                e0[r] = __builtin_amdgcn_exp2f(Sh[m][0][r]);
                e1[r] = __builtin_amdgcn_exp2f(Sh[m][1][r]);
            }
            unsigned A0 = cvt_pk_bf16(e0[0], e0[1]);
            unsigned A1 = cvt_pk_bf16(e0[2], e0[3]);
            unsigned B0 = cvt_pk_bf16(e1[0], e1[1]);
            unsigned B1 = cvt_pk_bf16(e1[2], e1[3]);
            asm("v_permlane32_swap_b32 %0, %1" : "+v"(A0), "+v"(B0));
            asm("v_permlane16_swap_b32 %0, %1" : "+v"(A0), "+v"(B0));
            asm("v_permlane32_swap_b32 %0, %1" : "+v"(A1), "+v"(B1));
            asm("v_permlane16_swap_b32 %0, %1" : "+v"(A1), "+v"(B1));
            uint4v pw = { A0, A1, B0, B1 };
            paD[m] = *(short8*)&pw;
            Ol[m] = __builtin_amdgcn_mfma_f32_16x16x32_bf16(paD[m], ones, Ol[m], 0, 0, 0);
        }
    };

    stage(0, 0);
    int cur = 0;
    for (int j0 = 0; j0 < LL; j0 += 64) {
        __syncthreads();                      // buf[cur] DMA drained; prev reads of buf[cur^1] done
        if (j0 + 64 < LL) stage(j0 + 64, cur ^ 1);

        const unsigned short* kbp = kt[cur];
        const unsigned short* vbp = vt[cur];

        floatx4 Sa[2][2], Sb[2][2];
#pragma unroll
        for (int m = 0; m < 2; ++m)
#pragma unroll
            for (int nt = 0; nt < 2; ++nt) { Sa[m][nt] = {0.f,0.f,0.f,0.f}; Sb[m][nt] = {0.f,0.f,0.f,0.f}; }

        // ---- S half0 (j 0..31) ----
        short8 ka0 = *(const short8*)(kbp + kro[0]);
        short8 ka1 = *(const short8*)(kbp + kro[1]);
        short8 kb0 = *(const short8*)(kbp + kro[0] + 1024);
        short8 kb1 = *(const short8*)(kbp + kro[1] + 1024);
#pragma unroll
        for (int m = 0; m < 2; ++m) {
            Sa[m][0] = __builtin_amdgcn_mfma_f32_16x16x32_bf16(ka0, qf[m][0], Sa[m][0], 0, 0, 0);
            Sa[m][0] = __builtin_amdgcn_mfma_f32_16x16x32_bf16(ka1, qf[m][1], Sa[m][0], 0, 0, 0);
            Sa[m][1] = __builtin_amdgcn_mfma_f32_16x16x32_bf16(kb0, qf[m][0], Sa[m][1], 0, 0, 0);
            Sa[m][1] = __builtin_amdgcn_mfma_f32_16x16x32_bf16(kb1, qf[m][1], Sa[m][1], 0, 0, 0);
        }
        // ---- S half1 (j 32..63) ----
        short8 kc0 = *(const short8*)(kbp + kro[0] + 2048);
        short8 kc1 = *(const short8*)(kbp + kro[1] + 2048);
        short8 kd0 = *(const short8*)(kbp + kro[0] + 3072);
        short8 kd1 = *(const short8*)(kbp + kro[1] + 3072);
#pragma unroll
        for (int m = 0; m < 2; ++m) {
            Sb[m][0] = __builtin_amdgcn_mfma_f32_16x16x32_bf16(kc0, qf[m][0], Sb[m][0], 0, 0, 0);
            Sb[m][0] = __builtin_amdgcn_mfma_f32_16x16x32_bf16(kc1, qf[m][1], Sb[m][0], 0, 0, 0);
            Sb[m][1] = __builtin_amdgcn_mfma_f32_16x16x32_bf16(kd0, qf[m][0], Sb[m][1], 0, 0, 0);
            Sb[m][1] = __builtin_amdgcn_mfma_f32_16x16x32_bf16(kd1, qf[m][1], Sb[m][1], 0, 0, 0);
        }

        short8 pa0[2], pa1[2];
        softmax_half(Sa, pa0);     // independent of Sb MFMAs -> scheduler overlaps

        // ---- PV half0, first 8 c-tiles ----
        __builtin_amdgcn_s_setprio(1);
#pragma unroll
        for (int nt = 0; nt < 8; ++nt) {
            short8 vf = *(const short8*)(vbp + vro[0] + nt * 1024);
#pragma unroll
            for (int m = 0; m < 2; ++m)
                O[m][nt] = __builtin_amdgcn_mfma_f32_16x16x32_bf16(pa0[m], vf, O[m][nt], 0, 0, 0);
        }
        __builtin_amdgcn_s_setprio(0);

        softmax_half(Sb, pa1);     // overlaps PV-half0 tail / next PV issue

        __builtin_amdgcn_s_setprio(1);
#pragma unroll
        for (int nt = 8; nt < 16; ++nt) {
            short8 vf = *(const short8*)(vbp + vro[0] + nt * 1024);
#pragma unroll
            for (int m = 0; m < 2; ++m)
                O[m][nt] = __builtin_amdgcn_mfma_f32_16x16x32_bf16(pa0[m], vf, O[m][nt], 0, 0, 0);
        }
#pragma unroll
        for (int nt = 0; nt < 16; ++nt) {
            short8 vf = *(const short8*)(vbp + vro[1] + nt * 1024);
#pragma unroll
            for (int m = 0; m < 2; ++m)
                O[m][nt] = __builtin_amdgcn_mfma_f32_16x16x32_bf16(pa1[m], vf, O[m][nt], 0, 0, 0);
        }
        __builtin_amdgcn_s_setprio(0);
        cur ^= 1;
    }

    // ---- epilogue: out = gamma * O / l + x ----
    float linv[2][4];
#pragma unroll
    for (int m = 0; m < 2; ++m)
#pragma unroll
        for (int r = 0; r < 4; ++r) linv[m][r] = 1.f / Ol[m][r];

    float gam = gamma[0];
#pragma unroll
    for (int m = 0; m < 2; ++m)
#pragma unroll
        for (int nt = 0; nt < 16; ++nt) {
            int c = c0 + nt * 16 + lane16;
            size_t base = ((size_t)b * CC + c) * LL + iw + m * 16 + g * 4;
            floatx4 xv = *(const floatx4*)(x + base);
            floatx4 o;
#pragma unroll
            for (int r = 0; r < 4; ++r) o[r] = gam * (O[m][nt][r] * linv[m][r]) + xv[r];
            *(floatx4*)(out + base) = o;
        }
}

extern "C" void kernel_launch(void* const* d_in, const int* in_sizes, int n_in,
                              void* d_out, int out_size, void* d_ws, size_t ws_size,
                              hipStream_t stream) {
    const float* x     = (const float*)d_in[0];
    const float* Wq    = (const float*)d_in[1];
    const float* bq    = (const float*)d_in[2];
    const float* Wk    = (const float*)d_in[3];
    const float* bk    = (const float*)d_in[4];
    const float* Wv    = (const float*)d_in[5];
    const float* bv    = (const float*)d_in[6];
    const float* gamma = (const float*)d_in[7];
    float* out = (float*)d_out;

    unsigned short* xt  = (unsigned short*)d_ws;          // B*L*C      = 16,777,216
    unsigned short* qb  = xt  + (size_t)BB * LL * CC;     // B*L*64     =  2,097,152
    unsigned short* kb  = qb  + (size_t)BB * LL * DQK;
    unsigned short* vb  = kb  + (size_t)BB * LL * DQK;    // B*C*L      = 16,777,216
    unsigned short* wqb = vb  + (size_t)BB * CC * LL;     // 32768
    unsigned short* wkb = wqb + (size_t)DQK * CC;
    unsigned short* wvb = wkb + (size_t)DQK * CC;         // 262144

    k_transpose<<<dim3(LL / 64, CC / 64, BB), 256, 0, stream>>>(x, xt);
    k_castw<<<dim3((CC * CC) / 256), 256, 0, stream>>>(Wq, Wk, Wv, wqb, wkb, wvb);
    k_projall<<<dim3(LL / 64, BB), 256, 0, stream>>>(xt, wqb, wkb, wvb, bq, bk, bv, qb, kb, vb);
    k_attn<<<dim3(LL / 128, BB, CC / 256), 256, 0, stream>>>(qb, kb, vb, x, gamma, out);
}